// Round 6
// baseline (139.495 us; speedup 1.0000x reference)
//
#include <hip/hip_runtime.h>
#include <hip/hip_bf16.h>
#include <math.h>

#define NPTS 65536
#define MRAY 16
#define BLOCK 256
#define PPW 4
#define PPB 16
#define GRID 4096

typedef float f2 __attribute__((ext_vector_type(2)));
typedef float f32x4 __attribute__((ext_vector_type(4)));
typedef _Float16 h8 __attribute__((ext_vector_type(8)));

__device__ __forceinline__ f2 fma2(f2 a, f2 b, f2 c){
#if __has_builtin(__builtin_elementwise_fma)
    return __builtin_elementwise_fma(a, b, c);
#else
    f2 r; r.x = fmaf(a.x, b.x, c.x); r.y = fmaf(a.y, b.y, c.y); return r;
#endif
}
__device__ __forceinline__ float sigmoidf_(float x){ return 1.0f/(1.0f+__expf(-x)); }
__device__ __forceinline__ float wsum64(float x){
  x += __shfl_xor(x,1); x += __shfl_xor(x,2); x += __shfl_xor(x,4);
  x += __shfl_xor(x,8); x += __shfl_xor(x,16); x += __shfl_xor(x,32);
  return x;
}
__device__ __forceinline__ float sel4(float a, float b, float c, float d, int p){
  float lo = (p&1) ? b : a;
  float hi = (p&1) ? d : c;
  return (p&2) ? hi : lo;
}
__device__ __forceinline__ f2 shflxor2(f2 v, int off){
  f2 r; r.x = __shfl_xor(v.x, off); r.y = __shfl_xor(v.y, off); return r;
}

// prep: classify ray_mask dtype (ws[0] as int).
// flag: 0 = 1-byte (uint8 bool), 1 = 4-byte word (int32/float32; !=0 decode), 2 = 8-byte (int64)
__global__ void prep(const unsigned int* __restrict__ rm, float* __restrict__ ws) {
    if (threadIdx.x == 0){
        bool bad = false, isf32 = false, odd_nz = false, even_one = false;
        for (int i = 0; i < 512; i++) {
            unsigned v = rm[i];
            if (v != 0u && v != 1u && v != 0x3F800000u) bad = true;
            if (v == 0x3F800000u) isf32 = true;
            if ((i & 1) && v != 0u) odd_nz = true;
            if (!(i & 1) && v != 0u) even_one = true;
        }
        int f;
        if (bad) f = 0;
        else if (isf32) f = 1;
        else if (!odd_nz && even_one) f = 2;
        else f = 1;
        ((int*)ws)[0] = f;
    }
}

__global__ __launch_bounds__(BLOCK, 4) void rb_main(
    const float* __restrict__ xyzs, const float* __restrict__ app,
    const float* __restrict__ vdirs, const float* __restrict__ normals,
    const float* __restrict__ noise, const float* __restrict__ uu,
    const float* __restrict__ Wd1, const float* __restrict__ bd1,
    const float* __restrict__ Wd2, const float* __restrict__ bd2,
    const float* __restrict__ Wb1, const float* __restrict__ bb1,
    const float* __restrict__ Wb2, const float* __restrict__ bb2,
    const void* __restrict__ raym, const float* __restrict__ wsf,
    float* __restrict__ out)
{
    __shared__ float baseu[PPB*132];      // 16 pts x 132 (nf staging then base vectors)
    __shared__ h8    bfrag_lds[8*64];     // B fragments: 8 N-tiles, f16, frag layout
    __shared__ float wb2t_lds[3*128];     // Wb2 transposed

    const int tid  = threadIdx.x;
    const int lane = tid & 63;
    const int wid  = __builtin_amdgcn_readfirstlane(tid >> 6);
    const int pbase = blockIdx.x * PPB + wid * PPW;
    float* nfw = &baseu[wid * (PPW*132)];

    const int flag = ((const int*)wsf)[0];

    // ---- block init: B fragments (Wb1 ray rows {3,4,5,9..14} -> f16 frag layout) + Wb2^T ----
    for (int e = tid; e < 512; e += BLOCK){
        int t = e >> 6, l = e & 63;
        int gg = l >> 4, cc = l & 15;
        h8 v;
        #pragma unroll
        for (int b = 0; b < 8; b++){
            int k = 8*gg + b;
            float w = 0.f;
            if (k < 9){ int row = (k < 3) ? (k + 3) : (k + 6); w = Wb1[row*128 + 16*t + cc]; }
            v[b] = (_Float16)w;
        }
        bfrag_lds[e] = v;
    }
    for (int i = tid; i < 384; i += BLOCK){
        int c = i >> 7, j = i & 127;
        wb2t_lds[c*128 + j] = Wb2[j*3 + c];
    }
    __syncthreads();

    // ---- phase 1: basis + local V (lanes 0..3) + noise-features ----
    float bs[12];
    #pragma unroll
    for (int i = 0; i < 12; i++) bs[i] = 0.f;
    if (lane < PPW){
        int n = pbase + lane;
        float nx = normals[n*3+0], ny = normals[n*3+1], nz = normals[n*3+2];
        float inv = 1.0f/(sqrtf(nx*nx+ny*ny+nz*nz)+1e-8f);
        float bx = nx*inv, by = ny*inv, bz = nz*inv;
        float ux, uy, uz;
        if (fabsf(bz) < 0.99f){ ux=0.f; uy=0.f; uz=1.f; } else { ux=1.f; uy=0.f; uz=0.f; }
        float tx = uy*bz-uz*by, ty = uz*bx-ux*bz, tz = ux*by-uy*bx;
        float tin = 1.0f/(sqrtf(tx*tx+ty*ty+tz*tz)+1e-8f);
        tx*=tin; ty*=tin; tz*=tin;
        float ex = by*tz-bz*ty, ey = bz*tx-bx*tz, ez = bx*ty-by*tx;
        bs[0]=tx; bs[1]=ex; bs[2]=bx; bs[3]=ty; bs[4]=ey; bs[5]=by; bs[6]=tz; bs[7]=ez; bs[8]=bz;
        float vx = vdirs[n*3+0], vy = vdirs[n*3+1], vz = vdirs[n*3+2];
        bs[9]  = -(tx*vx + ty*vy + tz*vz);
        bs[10] = -(ex*vx + ey*vy + ez*vz);
        bs[11] = -(bx*vx + by*vy + bz*vz);
    }
    #pragma unroll
    for (int c = 0; c < 3; c++){
        int idx = lane + 64*c;
        float v = fmaf(0.01f, noise[pbase*48 + idx], app[pbase*48 + idx]);
        int p = idx / 48, k = idx - 48*p;
        nfw[k*4 + p] = v;
    }

    // ---- phase 2: dense layer1 + bounce const part (lane = hidden unit, 4 pts as 2 f2-pairs) ----
    f2 h2[2][2], b2[2][2];
    {
        float h0 = bd1[lane], h1 = bd1[lane+64];
        float c0 = bb1[lane], c1 = bb1[lane+64];
        #pragma unroll
        for (int q = 0; q < 2; q++){
            h2[q][0] = f2{h0,h0}; h2[q][1] = f2{h1,h1};
            b2[q][0] = f2{c0,c0}; b2[q][1] = f2{c1,c1};
        }
    }
    float vd[PPW][3];
    #pragma unroll
    for (int k = 0; k < 3; k++){
        float w0 = Wd1[k*128+lane], w1 = Wd1[k*128+64+lane];
        f2 sA = { xyzs[(pbase+0)*3+k], xyzs[(pbase+1)*3+k] };
        f2 sB = { xyzs[(pbase+2)*3+k], xyzs[(pbase+3)*3+k] };
        h2[0][0]=fma2(sA,f2{w0,w0},h2[0][0]); h2[0][1]=fma2(sA,f2{w1,w1},h2[0][1]);
        h2[1][0]=fma2(sB,f2{w0,w0},h2[1][0]); h2[1][1]=fma2(sB,f2{w1,w1},h2[1][1]);
    }
    #pragma unroll
    for (int k = 0; k < 3; k++){
        float w0 = Wd1[(3+k)*128+lane], w1 = Wd1[(3+k)*128+64+lane];
        #pragma unroll
        for (int p = 0; p < PPW; p++) vd[p][k] = vdirs[(pbase+p)*3+k];
        f2 sA = { vd[0][k], vd[1][k] };
        f2 sB = { vd[2][k], vd[3][k] };
        h2[0][0]=fma2(sA,f2{w0,w0},h2[0][0]); h2[0][1]=fma2(sA,f2{w1,w1},h2[0][1]);
        h2[1][0]=fma2(sB,f2{w0,w0},h2[1][0]); h2[1][1]=fma2(sB,f2{w1,w1},h2[1][1]);
    }
    #pragma unroll 8
    for (int k = 0; k < 48; k++){
        float w0 = Wd1[(6+k)*128+lane], w1 = Wd1[(6+k)*128+64+lane];
        f2 sA = { app[(pbase+0)*48+k], app[(pbase+1)*48+k] };
        f2 sB = { app[(pbase+2)*48+k], app[(pbase+3)*48+k] };
        h2[0][0]=fma2(sA,f2{w0,w0},h2[0][0]); h2[0][1]=fma2(sA,f2{w1,w1},h2[0][1]);
        h2[1][0]=fma2(sB,f2{w0,w0},h2[1][0]); h2[1][1]=fma2(sB,f2{w1,w1},h2[1][1]);
    }
    #pragma unroll
    for (int s = 0; s < 3; s++){
        float w0 = Wb1[s*128+lane], w1 = Wb1[s*128+64+lane];
        f2 sA = { -vd[0][s], -vd[1][s] };
        f2 sB = { -vd[2][s], -vd[3][s] };
        b2[0][0]=fma2(sA,f2{w0,w0},b2[0][0]); b2[0][1]=fma2(sA,f2{w1,w1},b2[0][1]);
        b2[1][0]=fma2(sB,f2{w0,w0},b2[1][0]); b2[1][1]=fma2(sB,f2{w1,w1},b2[1][1]);
    }
    #pragma unroll
    for (int s = 0; s < 3; s++){
        float w0 = Wb1[(6+s)*128+lane], w1 = Wb1[(6+s)*128+64+lane];
        float bn0 = __shfl(bs[3*s+2], 0), bn1 = __shfl(bs[3*s+2], 1);
        float bn2 = __shfl(bs[3*s+2], 2), bn3 = __shfl(bs[3*s+2], 3);
        f2 sA = { bn0, bn1 }, sB = { bn2, bn3 };
        b2[0][0]=fma2(sA,f2{w0,w0},b2[0][0]); b2[0][1]=fma2(sA,f2{w1,w1},b2[0][1]);
        b2[1][0]=fma2(sB,f2{w0,w0},b2[1][0]); b2[1][1]=fma2(sB,f2{w1,w1},b2[1][1]);
    }
    const f2* nfp = (const f2*)nfw;
    #pragma unroll 8
    for (int k = 0; k < 48; k++){
        float w0 = Wb1[(15+k)*128+lane], w1 = Wb1[(15+k)*128+64+lane];
        f2 nA = nfp[k*2+0], nB = nfp[k*2+1];
        b2[0][0]=fma2(nA,f2{w0,w0},b2[0][0]); b2[0][1]=fma2(nA,f2{w1,w1},b2[0][1]);
        b2[1][0]=fma2(nB,f2{w0,w0},b2[1][0]); b2[1][1]=fma2(nB,f2{w1,w1},b2[1][1]);
    }

    float wd2v[2][4];
    #pragma unroll
    for (int r = 0; r < 2; r++){
        int j = lane + 64*r;
        wd2v[r][0]=Wd2[j*9+0]; wd2v[r][1]=Wd2[j*9+1]; wd2v[r][2]=Wd2[j*9+2]; wd2v[r][3]=Wd2[j*9+6];
    }
    const float sbd2_0=bd2[0], sbd2_1=bd2[1], sbd2_2=bd2[2], sbd2_6=bd2[6];
    float hr[PPW][2];
    hr[0][0]=fmaxf(h2[0][0].x,0.f); hr[0][1]=fmaxf(h2[0][1].x,0.f);
    hr[1][0]=fmaxf(h2[0][0].y,0.f); hr[1][1]=fmaxf(h2[0][1].y,0.f);
    hr[2][0]=fmaxf(h2[1][0].x,0.f); hr[2][1]=fmaxf(h2[1][1].x,0.f);
    hr[3][0]=fmaxf(h2[1][0].y,0.f); hr[3][1]=fmaxf(h2[1][1].y,0.f);
    float dif[PPW][3], r1v[PPW], a2v[PPW], sclv[PPW];
    #pragma unroll
    for (int p = 0; p < PPW; p++){
        float d0 = wsum64(fmaf(hr[p][0],wd2v[0][0], hr[p][1]*wd2v[1][0])) + sbd2_0;
        float d1 = wsum64(fmaf(hr[p][0],wd2v[0][1], hr[p][1]*wd2v[1][1])) + sbd2_1;
        float d2 = wsum64(fmaf(hr[p][0],wd2v[0][2], hr[p][1]*wd2v[1][2])) + sbd2_2;
        float d6 = wsum64(fmaf(hr[p][0],wd2v[0][3], hr[p][1]*wd2v[1][3])) + sbd2_6;
        dif[p][0]=sigmoidf_(d0); dif[p][1]=sigmoidf_(d1); dif[p][2]=sigmoidf_(d2);
        float r1 = sigmoidf_(d6)*0.98f + 0.01f;
        float a2 = r1*r1; a2 = a2*a2;
        r1v[p]=r1; a2v[p]=a2;
        sclv[p]=__expf(0.1f*__logf(fmaxf(a2,1e-6f)));
    }
    {
        float w0 = Wb1[63*128+lane], w1 = Wb1[63*128+64+lane];
        float bl[PPW][2];
        bl[0][0]=b2[0][0].x; bl[0][1]=b2[0][1].x;
        bl[1][0]=b2[0][0].y; bl[1][1]=b2[0][1].y;
        bl[2][0]=b2[1][0].x; bl[2][1]=b2[1][1].x;
        bl[3][0]=b2[1][0].y; bl[3][1]=b2[1][1].y;
        #pragma unroll
        for (int p = 0; p < PPW; p++){
            baseu[(wid*PPW+p)*132 + lane]      = fmaf(r1v[p], w0, bl[p][0]);
            baseu[(wid*PPW+p)*132 + 64 + lane] = fmaf(r1v[p], w1, bl[p][1]);
        }
    }

    // ---- phase 3a: per-ray geometry (lane = p*16 + m); rv stays in registers ----
    const int g   = lane >> 4;
    const int c15 = lane & 15;
    float rv[9];
    {
        const int n = pbase + g;
        float bas[9];
        #pragma unroll
        for (int i = 0; i < 9; i++) bas[i] = __shfl(bs[i], g);
        float Vlx = __shfl(bs[9],  g);
        float Vly = __shfl(bs[10], g);
        float Vlz = __shfl(bs[11], g);
        float a2s = sel4(a2v[0],a2v[1],a2v[2],a2v[3],g);

        float u1 = uu[(n*MRAY+c15)*2+0];
        float u2 = uu[(n*MRAY+c15)*2+1];
        float ct = sqrtf((1.0f-u1)/(1.0f+(a2s-1.0f)*u1));
        float st = sqrtf(fmaxf(1.0f-ct*ct,0.0f));
        float phi = 6.28318530717958647692f*u2;
        float hl0 = st*__cosf(phi), hl1 = st*__sinf(phi), hl2 = ct;
        float dvh = Vlx*hl0 + Vly*hl1 + Vlz*hl2;
        float t2 = dvh + dvh;
        float llx = fmaf(t2,hl0,-Vlx), lly = fmaf(t2,hl1,-Vly), llz = fmaf(t2,hl2,-Vlz);
        float linv = 1.0f/(sqrtf(llx*llx+lly*lly+llz*llz)+1e-8f);
        llx*=linv; lly*=linv; llz*=linv;
        rv[0] = bas[0]*llx + bas[1]*lly + bas[2]*llz;
        rv[1] = bas[3]*llx + bas[4]*lly + bas[5]*llz;
        rv[2] = bas[6]*llx + bas[7]*lly + bas[8]*llz;
        rv[3] = hl0; rv[4] = hl1; rv[5] = hl2;
        rv[6] = llx; rv[7] = lly; rv[8] = llz;
    }

    // ---- phase 3b: A fragments via lane shuffles (no LDS), MFMA over 8 N-tiles ----
    h8 af[PPW];
    #pragma unroll
    for (int p = 0; p < PPW; p++){
        const int srcl = p*16 + c15;
        float t0 = __shfl(rv[0], srcl), t1 = __shfl(rv[1], srcl);
        float t2_ = __shfl(rv[2], srcl), t3 = __shfl(rv[3], srcl);
        float t4 = __shfl(rv[4], srcl), t5 = __shfl(rv[5], srcl);
        float t6 = __shfl(rv[6], srcl), t7 = __shfl(rv[7], srcl);
        float t8 = __shfl(rv[8], srcl);
        const bool g0 = (g == 0), g1 = (g == 1);
        h8 a;
        a[0] = (_Float16)(g0 ? t0 : (g1 ? t8 : 0.f));
        a[1] = (_Float16)(g0 ? t1 : 0.f);
        a[2] = (_Float16)(g0 ? t2_ : 0.f);
        a[3] = (_Float16)(g0 ? t3 : 0.f);
        a[4] = (_Float16)(g0 ? t4 : 0.f);
        a[5] = (_Float16)(g0 ? t5 : 0.f);
        a[6] = (_Float16)(g0 ? t6 : 0.f);
        a[7] = (_Float16)(g0 ? t7 : 0.f);
        af[p] = a;
    }

    f2 part[PPW][2][3];
    #pragma unroll
    for (int p = 0; p < PPW; p++)
        #pragma unroll
        for (int q = 0; q < 2; q++)
            #pragma unroll
            for (int c = 0; c < 3; c++) part[p][q][c] = f2{0.f,0.f};

    #pragma unroll
    for (int t = 0; t < 8; t++){
        h8 bf = bfrag_lds[t*64 + lane];
        const int j = 16*t + c15;
        float w0 = wb2t_lds[0*128 + j];
        float w1 = wb2t_lds[1*128 + j];
        float w2 = wb2t_lds[2*128 + j];
        #pragma unroll
        for (int p = 0; p < PPW; p++){
            float cb = baseu[(wid*PPW+p)*132 + j];
            f32x4 cc = {cb, cb, cb, cb};
            f32x4 d = __builtin_amdgcn_mfma_f32_16x16x32_f16(af[p], bf, cc, 0, 0, 0);
            f32x4 z = {0.f,0.f,0.f,0.f};
            d = __builtin_elementwise_max(d, z);
            f2 d01 = { d.x, d.y };
            f2 d23 = { d.z, d.w };
            part[p][0][0] = fma2(d01, f2{w0,w0}, part[p][0][0]);
            part[p][1][0] = fma2(d23, f2{w0,w0}, part[p][1][0]);
            part[p][0][1] = fma2(d01, f2{w1,w1}, part[p][0][1]);
            part[p][1][1] = fma2(d23, f2{w1,w1}, part[p][1][1]);
            part[p][0][2] = fma2(d01, f2{w2,w2}, part[p][0][2]);
            part[p][1][2] = fma2(d23, f2{w2,w2}, part[p][1][2]);
        }
    }

    // ---- phase 3c: reduce-scatter over the 16 j-lanes; lane ends owning ray (p,(lane>>4)*4+(lane&3)) ----
    const bool b8 = (lane & 8) != 0;
    const bool b4 = (lane & 4) != 0;
    const bool b2f = (lane & 2) != 0;
    const bool b1 = (lane & 1) != 0;
    f2 k1[2][2][3];
    #pragma unroll
    for (int pp = 0; pp < 2; pp++)
      #pragma unroll
      for (int q = 0; q < 2; q++)
        #pragma unroll
        for (int c = 0; c < 3; c++){
            f2 lo = part[pp][q][c], hi = part[2+pp][q][c];
            f2 sent = b8 ? lo : hi;
            f2 got  = shflxor2(sent, 8);
            f2 mine = b8 ? hi : lo;
            k1[pp][q][c] = mine + got;
        }
    f2 k2[2][3];
    #pragma unroll
    for (int q = 0; q < 2; q++)
      #pragma unroll
      for (int c = 0; c < 3; c++){
          f2 lo = k1[0][q][c], hi = k1[1][q][c];
          f2 sent = b4 ? lo : hi;
          f2 got  = shflxor2(sent, 4);
          f2 mine = b4 ? hi : lo;
          k2[q][c] = mine + got;
      }
    f2 k3[3];
    #pragma unroll
    for (int c = 0; c < 3; c++){
        f2 lo = k2[0][c], hi = k2[1][c];
        f2 sent = b2f ? lo : hi;
        f2 got  = shflxor2(sent, 2);
        f2 mine = b2f ? hi : lo;
        k3[c] = mine + got;
    }
    float S[3];
    #pragma unroll
    for (int c = 0; c < 3; c++){
        f2 got = shflxor2(k3[c], 1);
        float m_ = b1 ? k3[c].y : k3[c].x;
        float g_ = b1 ? got.y   : got.x;
        S[c] = m_ + g_;
    }

    // ---- phase 3d: epilogue on new mapping (p = (lane>>2)&3, ray = 4*(lane>>4)+(lane&3)) ----
    {
        const int p  = (lane >> 2) & 3;
        const int mr = 4*(lane >> 4) + (lane & 3);
        const int srcl = p*16 + mr;
        float lzw = __shfl(rv[2], srcl);
        float scl = sel4(sclv[0],sclv[1],sclv[2],sclv[3], p);
        float e0 = sigmoidf_(S[0] + bb2[0]);
        float e1 = sigmoidf_(S[1] + bb2[1]);
        float e2 = sigmoidf_(S[2] + bb2[2]);
        int midx = (pbase + p)*MRAY + mr;
        bool mk;
        if (flag == 0)      mk = ((const unsigned char*)raym)[midx] != 0;
        else if (flag == 2) mk = ((const unsigned long long*)raym)[midx] != 0ull;
        else                mk = ((const unsigned int*)raym)[midx] != 0u;
        float mf = mk ? 1.f : 0.f;
        float lzp = fmaxf(lzw, 0.f);
        float c0 = (lzp*1.0f+0.1f)*scl*e0*mf;
        float c1 = (lzp*0.9f+0.1f)*scl*e1*mf;
        float c2 = (lzp*0.8f+0.1f)*scl*e2*mf;
        c0 += __shfl_xor(c0,1);  c1 += __shfl_xor(c1,1);  c2 += __shfl_xor(c2,1);  mf += __shfl_xor(mf,1);
        c0 += __shfl_xor(c0,2);  c1 += __shfl_xor(c1,2);  c2 += __shfl_xor(c2,2);  mf += __shfl_xor(mf,2);
        c0 += __shfl_xor(c0,16); c1 += __shfl_xor(c1,16); c2 += __shfl_xor(c2,16); mf += __shfl_xor(mf,16);
        c0 += __shfl_xor(c0,32); c1 += __shfl_xor(c1,32); c2 += __shfl_xor(c2,32); mf += __shfl_xor(mf,32);
        if ((lane & 0x33) == 0){
            const int pw = lane >> 2;
            const int n2 = pbase + pw;
            float den = mf + 1e-8f;
            out[n2*3+0] = c0/den + sel4(dif[0][0],dif[1][0],dif[2][0],dif[3][0],pw);
            out[n2*3+1] = c1/den + sel4(dif[0][1],dif[1][1],dif[2][1],dif[3][1],pw);
            out[n2*3+2] = c2/den + sel4(dif[0][2],dif[1][2],dif[2][2],dif[3][2],pw);
        }
    }
}

extern "C" void kernel_launch(void* const* d_in, const int* in_sizes, int n_in,
                              void* d_out, int out_size, void* d_ws, size_t ws_size,
                              hipStream_t stream) {
    const float* xyzs    = (const float*)d_in[0];
    const float* app     = (const float*)d_in[1];
    const float* vdirs   = (const float*)d_in[2];
    const float* normals = (const float*)d_in[3];
    const float* noise   = (const float*)d_in[4];
    const float* uu      = (const float*)d_in[5];
    const float* Wd1     = (const float*)d_in[6];
    const float* bd1     = (const float*)d_in[7];
    const float* Wd2     = (const float*)d_in[8];
    const float* bd2     = (const float*)d_in[9];
    const float* Wb1     = (const float*)d_in[10];
    const float* bb1     = (const float*)d_in[11];
    const float* Wb2     = (const float*)d_in[12];
    const float* bb2     = (const float*)d_in[13];
    const void*  raym    = d_in[15];
    float* wsf = (float*)d_ws;
    float* out = (float*)d_out;

    prep<<<1, 64, 0, stream>>>((const unsigned int*)raym, wsf);
    rb_main<<<GRID, BLOCK, 0, stream>>>(xyzs, app, vdirs, normals, noise, uu,
                                        Wd1, bd1, Wd2, bd2, Wb1, bb1, Wb2, bb2,
                                        raym, wsf, out);
}

// Round 7
// 70.561 us; speedup vs baseline: 1.9769x; 1.9769x over previous
//
#include <hip/hip_runtime.h>
#include <hip/hip_bf16.h>
#include <math.h>

#define MRAY 16
#define BLOCK 64
#define PPWAVE 16
#define GRID 4096   // 4096 blocks * 16 pts = 65536

typedef float f2 __attribute__((ext_vector_type(2)));
typedef float f4 __attribute__((ext_vector_type(4)));
typedef _Float16 h8 __attribute__((ext_vector_type(8)));

__device__ __forceinline__ f2 fma2(f2 a, f2 b, f2 c){ return __builtin_elementwise_fma(a,b,c); }
__device__ __forceinline__ float sigmoidf_(float x){ return 1.0f/(1.0f+__expf(-x)); }
__device__ __forceinline__ float sel4(float a,float b,float c,float d,int p){
    float lo = (p&1)? b : a;
    float hi = (p&1)? d : c;
    return (p&2)? hi : lo;
}
__device__ __forceinline__ f2 shflxor2(f2 v, int off){
    f2 r; r.x = __shfl_xor(v.x, off); r.y = __shfl_xor(v.y, off); return r;
}
__device__ __forceinline__ f4 mfma16(h8 a, h8 b, f4 c){
    return __builtin_amdgcn_mfma_f32_16x16x32_f16(a, b, c, 0, 0, 0);
}

// ws float layout:
//   [0]      flag (int)
//   [16]     fragD: h8[1024]  (Wd1, k-order [app48,xyz3,vdir3,pad10], 2 Ksteps x 8 tiles x 64 lanes)
//   [4112]   fragB: h8[1024]  (Wb1 const rows, k-order [nf48,eV3,eN3,pad10])
//   [8208]   fragR: h8[512]   (Wb1 ray rows {3,4,5,9..14}, K=32 single step)
//   [10256]  wpack: f4[128]   {Wb2^T[0..2][j], Wb1[63][j]}
//   [10768]  wd2pk: f4[128]   {Wd2[j][0],Wd2[j][1],Wd2[j][2],Wd2[j][6]}
__global__ __launch_bounds__(256) void prep(
    const float* __restrict__ Wd1, const float* __restrict__ Wb1,
    const float* __restrict__ Wb2, const float* __restrict__ Wd2,
    const unsigned int* __restrict__ rm, float* __restrict__ ws)
{
    const int gt = blockIdx.x*256 + threadIdx.x;
    h8* fragD = (h8*)(ws + 16);
    h8* fragB = fragD + 1024;
    h8* fragR = fragB + 1024;
    f4* wpack = (f4*)(ws + 10256);
    f4* wd2pk = (f4*)(ws + 10768);
    if (gt < 1024){
        int ks = gt >> 9, t = (gt >> 6) & 7, l = gt & 63;
        int col = 16*t + (l & 15), gg = (l >> 4) & 3;
        h8 v;
        #pragma unroll
        for (int b = 0; b < 8; b++){
            int k = 32*ks + 8*gg + b;
            int row = (k < 48) ? 6 + k : (k < 54 ? k - 48 : -1);
            v[b] = (_Float16)(row >= 0 ? Wd1[row*128 + col] : 0.0f);
        }
        fragD[gt] = v;
    } else if (gt < 2048){
        int e = gt - 1024;
        int ks = e >> 9, t = (e >> 6) & 7, l = e & 63;
        int col = 16*t + (l & 15), gg = (l >> 4) & 3;
        h8 v;
        #pragma unroll
        for (int b = 0; b < 8; b++){
            int k = 32*ks + 8*gg + b;
            int row = (k < 48) ? 15 + k : (k < 51 ? k - 48 : (k < 54 ? k - 45 : -1));
            v[b] = (_Float16)(row >= 0 ? Wb1[row*128 + col] : 0.0f);
        }
        fragB[e] = v;
    } else if (gt < 2560){
        int e = gt - 2048;
        int t = e >> 6, l = e & 63;
        int col = 16*t + (l & 15), gg = (l >> 4) & 3;
        h8 v;
        #pragma unroll
        for (int b = 0; b < 8; b++){
            int k = 8*gg + b;
            int row = (k < 3) ? 3 + k : (k < 9 ? 6 + k : -1);
            v[b] = (_Float16)(row >= 0 ? Wb1[row*128 + col] : 0.0f);
        }
        fragR[e] = v;
    } else if (gt < 2688){
        int j = gt - 2560;
        wpack[j] = f4{ Wb2[j*3+0], Wb2[j*3+1], Wb2[j*3+2], Wb1[63*128 + j] };
    } else if (gt < 2816){
        int j = gt - 2688;
        wd2pk[j] = f4{ Wd2[j*9+0], Wd2[j*9+1], Wd2[j*9+2], Wd2[j*9+6] };
    } else if (gt >= 3072 && gt < 3136){
        // one full wave (block 12, tids 0..63): classify ray_mask dtype
        int l = gt - 3072;
        bool bad=false, isf32=false, odd_nz=false, even_one=false;
        #pragma unroll
        for (int i = 0; i < 8; i++){
            int idx = l*8 + i;
            unsigned v = rm[idx];
            if (v != 0u && v != 1u && v != 0x3F800000u) bad = true;
            if (v == 0x3F800000u) isf32 = true;
            if ((idx & 1) && v != 0u) odd_nz = true;
            if (!(idx & 1) && v != 0u) even_one = true;
        }
        unsigned long long Bb = __ballot(bad);
        unsigned long long Bf = __ballot(isf32);
        unsigned long long Bo = __ballot(odd_nz);
        unsigned long long Be = __ballot(even_one);
        if (l == 0){
            int f;
            if (Bb) f = 0;            // uint8 bool
            else if (Bf) f = 1;       // f32 / i32 words
            else if (!Bo && Be) f = 2; // int64
            else f = 1;
            ((int*)ws)[0] = f;
        }
    }
}

// 1 wave per block, 16 points per wave. No __syncthreads anywhere.
__global__ __launch_bounds__(BLOCK, 4) void rb_main(
    const float* __restrict__ xyzs, const float* __restrict__ app,
    const float* __restrict__ vdirs, const float* __restrict__ normals,
    const float* __restrict__ noise, const float* __restrict__ uu,
    const float* __restrict__ bd1, const float* __restrict__ bd2,
    const float* __restrict__ bb1, const float* __restrict__ bb2,
    const void* __restrict__ raym, const float* __restrict__ wsf,
    float* __restrict__ out)
{
    __shared__ float baseu[PPWAVE*132];   // 8448 B: base[16 pts][128] (stride 132)

    const int lane = threadIdx.x;
    const int pbase = blockIdx.x * PPWAVE;
    const int flag = ((const int*)wsf)[0];
    const h8* fragD = (const h8*)(wsf + 16);
    const h8* fragB = fragD + 1024;
    const h8* fragR = fragB + 1024;
    const f4* wpack = (const f4*)(wsf + 10256);
    const f4* wd2pk = (const f4*)(wsf + 10768);

    const int c15 = lane & 15;
    const int kg  = lane >> 4;

    // ---- phase 1: basis + local V for pt = lane (lanes 0..15) ----
    float bs[12];
    #pragma unroll
    for (int i = 0; i < 12; i++) bs[i] = 0.f;
    if (lane < 16){
        int n = pbase + lane;
        float nx = normals[n*3+0], ny = normals[n*3+1], nz = normals[n*3+2];
        float inv = 1.0f/(sqrtf(nx*nx+ny*ny+nz*nz)+1e-8f);
        float bx = nx*inv, by = ny*inv, bz = nz*inv;
        float ux, uy, uz;
        if (fabsf(bz) < 0.99f){ ux=0.f; uy=0.f; uz=1.f; } else { ux=1.f; uy=0.f; uz=0.f; }
        float tx = uy*bz-uz*by, ty = uz*bx-ux*bz, tz = ux*by-uy*bx;
        float tin = 1.0f/(sqrtf(tx*tx+ty*ty+tz*tz)+1e-8f);
        tx*=tin; ty*=tin; tz*=tin;
        float ex = by*tz-bz*ty, ey = bz*tx-bx*tz, ez = bx*ty-by*tx;
        bs[0]=tx; bs[1]=ex; bs[2]=bx; bs[3]=ty; bs[4]=ey; bs[5]=by; bs[6]=tz; bs[7]=ez; bs[8]=bz;
        float vx = vdirs[n*3+0], vy = vdirs[n*3+1], vz = vdirs[n*3+2];
        bs[9]  = -(tx*vx + ty*vy + tz*vz);
        bs[10] = -(ex*vx + ey*vy + ez*vz);
        bs[11] = -(bx*vx + by*vy + bz*vz);
    }

    // ---- A-fragments (lane: pt = c15, k-slice = kg) ----
    const int n_p = pbase + c15;
    float xv0=0.f,xv1=0.f,xv2=0.f,vv0=0.f,vv1=0.f,vv2=0.f;
    if (kg == 2){
        xv0 = xyzs[n_p*3+0]; xv1 = xyzs[n_p*3+1]; xv2 = xyzs[n_p*3+2];
        vv0 = vdirs[n_p*3+0]; vv1 = vdirs[n_p*3+1]; vv2 = vdirs[n_p*3+2];
    }
    float bn0 = __shfl(bs[2], c15), bn1 = __shfl(bs[5], c15), bn2 = __shfl(bs[8], c15);
    const float* ap = app + n_p*48;
    const float* nz = noise + n_p*48;
    h8 afD[2], afB[2];
    #pragma unroll
    for (int ks = 0; ks < 2; ks++){
        const int k0 = 32*ks + 8*kg;
        h8 aD, aB;
        if (k0 <= 40){
            f4 a0 = *(const f4*)(ap + k0);
            f4 a1 = *(const f4*)(ap + k0 + 4);
            f4 z0 = *(const f4*)(nz + k0);
            f4 z1 = *(const f4*)(nz + k0 + 4);
            aD[0]=(_Float16)a0.x; aD[1]=(_Float16)a0.y; aD[2]=(_Float16)a0.z; aD[3]=(_Float16)a0.w;
            aD[4]=(_Float16)a1.x; aD[5]=(_Float16)a1.y; aD[6]=(_Float16)a1.z; aD[7]=(_Float16)a1.w;
            aB[0]=(_Float16)fmaf(0.01f,z0.x,a0.x); aB[1]=(_Float16)fmaf(0.01f,z0.y,a0.y);
            aB[2]=(_Float16)fmaf(0.01f,z0.z,a0.z); aB[3]=(_Float16)fmaf(0.01f,z0.w,a0.w);
            aB[4]=(_Float16)fmaf(0.01f,z1.x,a1.x); aB[5]=(_Float16)fmaf(0.01f,z1.y,a1.y);
            aB[6]=(_Float16)fmaf(0.01f,z1.z,a1.z); aB[7]=(_Float16)fmaf(0.01f,z1.w,a1.w);
        } else if (k0 == 48){
            aD[0]=(_Float16)xv0; aD[1]=(_Float16)xv1; aD[2]=(_Float16)xv2;
            aD[3]=(_Float16)vv0; aD[4]=(_Float16)vv1; aD[5]=(_Float16)vv2;
            aD[6]=(_Float16)0.0f; aD[7]=(_Float16)0.0f;
            aB[0]=(_Float16)(-vv0); aB[1]=(_Float16)(-vv1); aB[2]=(_Float16)(-vv2);
            aB[3]=(_Float16)bn0; aB[4]=(_Float16)bn1; aB[5]=(_Float16)bn2;
            aB[6]=(_Float16)0.0f; aB[7]=(_Float16)0.0f;
        } else {
            #pragma unroll
            for (int b = 0; b < 8; b++){ aD[b]=(_Float16)0.0f; aB[b]=(_Float16)0.0f; }
        }
        afD[ks]=aD; afB[ks]=aB;
    }

    // ---- GEMM1 (dense layer1) + layer-2 partials ----
    float P[4][4];
    #pragma unroll
    for (int r = 0; r < 4; r++){ P[r][0]=0.f; P[r][1]=0.f; P[r][2]=0.f; P[r][3]=0.f; }
    #pragma unroll 2
    for (int t = 0; t < 8; t++){
        const int col = 16*t + c15;
        float bias = bd1[col];
        f4 D = {bias,bias,bias,bias};
        D = mfma16(afD[0], fragD[t*64 + lane], D);
        D = mfma16(afD[1], fragD[512 + t*64 + lane], D);
        f4 z = {0.f,0.f,0.f,0.f};
        D = __builtin_elementwise_max(D, z);
        f4 w = wd2pk[col];
        P[0][0]=fmaf(D.x,w.x,P[0][0]); P[0][1]=fmaf(D.x,w.y,P[0][1]); P[0][2]=fmaf(D.x,w.z,P[0][2]); P[0][3]=fmaf(D.x,w.w,P[0][3]);
        P[1][0]=fmaf(D.y,w.x,P[1][0]); P[1][1]=fmaf(D.y,w.y,P[1][1]); P[1][2]=fmaf(D.y,w.z,P[1][2]); P[1][3]=fmaf(D.y,w.w,P[1][3]);
        P[2][0]=fmaf(D.z,w.x,P[2][0]); P[2][1]=fmaf(D.z,w.y,P[2][1]); P[2][2]=fmaf(D.z,w.z,P[2][2]); P[2][3]=fmaf(D.z,w.w,P[2][3]);
        P[3][0]=fmaf(D.w,w.x,P[3][0]); P[3][1]=fmaf(D.w,w.y,P[3][1]); P[3][2]=fmaf(D.w,w.z,P[3][2]); P[3][3]=fmaf(D.w,w.w,P[3][3]);
    }
    f2 pr[4][2];
    #pragma unroll
    for (int r = 0; r < 4; r++){ pr[r][0]=f2{P[r][0],P[r][1]}; pr[r][1]=f2{P[r][2],P[r][3]}; }
    #pragma unroll
    for (int off = 1; off <= 8; off <<= 1){
        #pragma unroll
        for (int r = 0; r < 4; r++){
            pr[r][0] += shflxor2(pr[r][0], off);
            pr[r][1] += shflxor2(pr[r][1], off);
        }
    }
    // this lane's scalars: pt = 4*kg + (lane&3)
    const int rq = lane & 3;
    float s0 = sel4(pr[0][0].x, pr[1][0].x, pr[2][0].x, pr[3][0].x, rq) + bd2[0];
    float s1 = sel4(pr[0][0].y, pr[1][0].y, pr[2][0].y, pr[3][0].y, rq) + bd2[1];
    float s2 = sel4(pr[0][1].x, pr[1][1].x, pr[2][1].x, pr[3][1].x, rq) + bd2[2];
    float s6 = sel4(pr[0][1].y, pr[1][1].y, pr[2][1].y, pr[3][1].y, rq) + bd2[6];
    float dv0 = sigmoidf_(s0), dv1 = sigmoidf_(s1), dv2 = sigmoidf_(s2);
    float r1v = sigmoidf_(s6)*0.98f + 0.01f;
    float a2v = r1v*r1v; a2v = a2v*a2v;
    float sclv = __expf(0.1f*__logf(fmaxf(a2v, 1e-6f)));

    // ---- GEMM2 (bounce const part) -> baseu ----
    #pragma unroll 2
    for (int t = 0; t < 8; t++){
        const int col = 16*t + c15;
        float bias = bb1[col];
        f4 D = {bias,bias,bias,bias};
        D = mfma16(afB[0], fragB[t*64 + lane], D);
        D = mfma16(afB[1], fragB[512 + t*64 + lane], D);
        baseu[(4*kg+0)*132 + col] = D.x;
        baseu[(4*kg+1)*132 + col] = D.y;
        baseu[(4*kg+2)*132 + col] = D.z;
        baseu[(4*kg+3)*132 + col] = D.w;
    }

    // ---- phase 3: 4 chunks of 4 points ----
    const float sbb2_0 = bb2[0], sbb2_1 = bb2[1], sbb2_2 = bb2[2];
    #pragma unroll 1
    for (int ch = 0; ch < 4; ch++){
        const int pt = 4*ch + kg;             // geometry point for this lane
        const int n = pbase + pt;
        float bas[9];
        #pragma unroll
        for (int i = 0; i < 9; i++) bas[i] = __shfl(bs[i], pt);
        float Vlx = __shfl(bs[9],  pt);
        float Vly = __shfl(bs[10], pt);
        float Vlz = __shfl(bs[11], pt);
        float a2s = __shfl(a2v, 16*ch + kg);

        f2 uv = *(const f2*)&uu[(n*MRAY + c15)*2];
        float ct = sqrtf((1.0f-uv.x)/(1.0f+(a2s-1.0f)*uv.x));
        float st = sqrtf(fmaxf(1.0f-ct*ct,0.0f));
        float phi = 6.28318530717958647692f*uv.y;
        float hl0 = st*__cosf(phi), hl1 = st*__sinf(phi), hl2 = ct;
        float dvh = Vlx*hl0 + Vly*hl1 + Vlz*hl2;
        float t2 = dvh + dvh;
        float llx = fmaf(t2,hl0,-Vlx), lly = fmaf(t2,hl1,-Vly), llz = fmaf(t2,hl2,-Vlz);
        float linv = 1.0f/(sqrtf(llx*llx+lly*lly+llz*llz)+1e-8f);
        llx*=linv; lly*=linv; llz*=linv;
        float rv[9];
        rv[0] = bas[0]*llx + bas[1]*lly + bas[2]*llz;
        rv[1] = bas[3]*llx + bas[4]*lly + bas[5]*llz;
        rv[2] = bas[6]*llx + bas[7]*lly + bas[8]*llz;
        rv[3] = hl0; rv[4] = hl1; rv[5] = hl2;
        rv[6] = llx; rv[7] = lly; rv[8] = llz;

        // A-fragments for the 4 points of this chunk (pure lane shuffles)
        h8 af[4];
        #pragma unroll
        for (int pp = 0; pp < 4; pp++){
            const int srcl = pp*16 + c15;
            float t0 = __shfl(rv[0], srcl), t1 = __shfl(rv[1], srcl);
            float t2_ = __shfl(rv[2], srcl), t3 = __shfl(rv[3], srcl);
            float t4 = __shfl(rv[4], srcl), t5 = __shfl(rv[5], srcl);
            float t6 = __shfl(rv[6], srcl), t7 = __shfl(rv[7], srcl);
            float t8 = __shfl(rv[8], srcl);
            const bool g0 = (kg == 0), g1 = (kg == 1);
            af[pp][0] = (_Float16)(g0 ? t0 : (g1 ? t8 : 0.f));
            af[pp][1] = (_Float16)(g0 ? t1 : 0.f);
            af[pp][2] = (_Float16)(g0 ? t2_ : 0.f);
            af[pp][3] = (_Float16)(g0 ? t3 : 0.f);
            af[pp][4] = (_Float16)(g0 ? t4 : 0.f);
            af[pp][5] = (_Float16)(g0 ? t5 : 0.f);
            af[pp][6] = (_Float16)(g0 ? t6 : 0.f);
            af[pp][7] = (_Float16)(g0 ? t7 : 0.f);
        }
        float r1p[4];
        #pragma unroll
        for (int pp = 0; pp < 4; pp++) r1p[pp] = __shfl(r1v, 16*ch + pp);

        f2 part[4][2][3];
        #pragma unroll
        for (int pp = 0; pp < 4; pp++)
            #pragma unroll
            for (int q = 0; q < 2; q++)
                #pragma unroll
                for (int c = 0; c < 3; c++) part[pp][q][c] = f2{0.f,0.f};

        #pragma unroll 2
        for (int t = 0; t < 8; t++){
            h8 bf = fragR[t*64 + lane];
            const int j = 16*t + c15;
            f4 wv = wpack[j];                       // {w0,w1,w2,w63}
            const float* brow = &baseu[(4*ch)*132 + j];
            #pragma unroll
            for (int pp = 0; pp < 4; pp++){
                float cb = brow[pp*132] + r1p[pp]*wv.w;
                f4 C = {cb,cb,cb,cb};
                f4 d = mfma16(af[pp], bf, C);
                f4 z = {0.f,0.f,0.f,0.f};
                d = __builtin_elementwise_max(d, z);
                f2 d01 = {d.x, d.y};
                f2 d23 = {d.z, d.w};
                part[pp][0][0] = fma2(d01, f2{wv.x,wv.x}, part[pp][0][0]);
                part[pp][1][0] = fma2(d23, f2{wv.x,wv.x}, part[pp][1][0]);
                part[pp][0][1] = fma2(d01, f2{wv.y,wv.y}, part[pp][0][1]);
                part[pp][1][1] = fma2(d23, f2{wv.y,wv.y}, part[pp][1][1]);
                part[pp][0][2] = fma2(d01, f2{wv.z,wv.z}, part[pp][0][2]);
                part[pp][1][2] = fma2(d23, f2{wv.z,wv.z}, part[pp][1][2]);
            }
        }

        // reduce-scatter over the 16 j-lanes; lane ends owning ray (p,(lane>>4)*4+(lane&3))
        const bool b8 = (lane & 8) != 0;
        const bool b4 = (lane & 4) != 0;
        const bool b2f = (lane & 2) != 0;
        const bool b1 = (lane & 1) != 0;
        f2 k1[2][2][3];
        #pragma unroll
        for (int pp = 0; pp < 2; pp++)
          #pragma unroll
          for (int q = 0; q < 2; q++)
            #pragma unroll
            for (int c = 0; c < 3; c++){
                f2 lo = part[pp][q][c], hi = part[2+pp][q][c];
                f2 sent = b8 ? lo : hi;
                f2 got  = shflxor2(sent, 8);
                f2 mine = b8 ? hi : lo;
                k1[pp][q][c] = mine + got;
            }
        f2 k2[2][3];
        #pragma unroll
        for (int q = 0; q < 2; q++)
          #pragma unroll
          for (int c = 0; c < 3; c++){
              f2 lo = k1[0][q][c], hi = k1[1][q][c];
              f2 sent = b4 ? lo : hi;
              f2 got  = shflxor2(sent, 4);
              f2 mine = b4 ? hi : lo;
              k2[q][c] = mine + got;
          }
        f2 k3[3];
        #pragma unroll
        for (int c = 0; c < 3; c++){
            f2 lo = k2[0][c], hi = k2[1][c];
            f2 sent = b2f ? lo : hi;
            f2 got  = shflxor2(sent, 2);
            f2 mine = b2f ? hi : lo;
            k3[c] = mine + got;
        }
        float S[3];
        #pragma unroll
        for (int c = 0; c < 3; c++){
            f2 got = shflxor2(k3[c], 1);
            float m_ = b1 ? k3[c].y : k3[c].x;
            float g_ = b1 ? got.y   : got.x;
            S[c] = m_ + g_;
        }

        // epilogue: p = (lane>>2)&3, ray = 4*(lane>>4)+(lane&3)
        {
            const int p  = (lane >> 2) & 3;
            const int mr = 4*(lane >> 4) + (lane & 3);
            const int srcl = p*16 + mr;
            float lzw = __shfl(rv[2], srcl);
            float scl = __shfl(sclv, 16*ch + p);
            // dif/scl for writer lanes (hoisted: shfl outside divergence)
            const int pw = lane >> 2;
            float dd0 = __shfl(dv0, 16*ch + (pw & 3));
            float dd1 = __shfl(dv1, 16*ch + (pw & 3));
            float dd2 = __shfl(dv2, 16*ch + (pw & 3));
            float e0 = sigmoidf_(S[0] + sbb2_0);
            float e1 = sigmoidf_(S[1] + sbb2_1);
            float e2 = sigmoidf_(S[2] + sbb2_2);
            int midx = (pbase + 4*ch + p)*MRAY + mr;
            bool mk;
            if (flag == 0)      mk = ((const unsigned char*)raym)[midx] != 0;
            else if (flag == 2) mk = ((const unsigned long long*)raym)[midx] != 0ull;
            else                mk = ((const unsigned int*)raym)[midx] != 0u;
            float mf = mk ? 1.f : 0.f;
            float lzp = fmaxf(lzw, 0.f);
            float c0 = (lzp*1.0f+0.1f)*scl*e0*mf;
            float c1 = (lzp*0.9f+0.1f)*scl*e1*mf;
            float c2 = (lzp*0.8f+0.1f)*scl*e2*mf;
            c0 += __shfl_xor(c0,1);  c1 += __shfl_xor(c1,1);  c2 += __shfl_xor(c2,1);  mf += __shfl_xor(mf,1);
            c0 += __shfl_xor(c0,2);  c1 += __shfl_xor(c1,2);  c2 += __shfl_xor(c2,2);  mf += __shfl_xor(mf,2);
            c0 += __shfl_xor(c0,16); c1 += __shfl_xor(c1,16); c2 += __shfl_xor(c2,16); mf += __shfl_xor(mf,16);
            c0 += __shfl_xor(c0,32); c1 += __shfl_xor(c1,32); c2 += __shfl_xor(c2,32); mf += __shfl_xor(mf,32);
            if ((lane & 0x33) == 0){
                const int n2 = pbase + 4*ch + pw;
                float den = mf + 1e-8f;
                out[n2*3+0] = c0/den + dd0;
                out[n2*3+1] = c1/den + dd1;
                out[n2*3+2] = c2/den + dd2;
            }
        }
    }
}

extern "C" void kernel_launch(void* const* d_in, const int* in_sizes, int n_in,
                              void* d_out, int out_size, void* d_ws, size_t ws_size,
                              hipStream_t stream) {
    const float* xyzs    = (const float*)d_in[0];
    const float* app     = (const float*)d_in[1];
    const float* vdirs   = (const float*)d_in[2];
    const float* normals = (const float*)d_in[3];
    const float* noise   = (const float*)d_in[4];
    const float* uu      = (const float*)d_in[5];
    const float* Wd1     = (const float*)d_in[6];
    const float* bd1     = (const float*)d_in[7];
    const float* Wd2     = (const float*)d_in[8];
    const float* bd2     = (const float*)d_in[9];
    const float* Wb1     = (const float*)d_in[10];
    const float* bb1     = (const float*)d_in[11];
    const float* Wb2     = (const float*)d_in[12];
    const float* bb2     = (const float*)d_in[13];
    const void*  raym    = d_in[15];
    float* wsf = (float*)d_ws;
    float* out = (float*)d_out;

    prep<<<16, 256, 0, stream>>>(Wd1, Wb1, Wb2, Wd2, (const unsigned int*)raym, wsf);
    rb_main<<<GRID, BLOCK, 0, stream>>>(xyzs, app, vdirs, normals, noise, uu,
                                        bd1, bd2, bb1, bb2,
                                        raym, wsf, out);
}